// Round 2
// baseline (6251.334 us; speedup 1.0000x reference)
//
#include <hip/hip_runtime.h>

typedef unsigned short u16;
typedef unsigned int u32;

// ---------- f32 -> bf16 RNE ----------
__device__ __forceinline__ u16 f2b(float f) {
  u32 u; __builtin_memcpy(&u, &f, 4);
  u32 r = (u + 0x7fffu + ((u >> 16) & 1u)) >> 16;
  return (u16)r;
}

using s16x8 = short __attribute__((ext_vector_type(8)));
using f32x4 = float __attribute__((ext_vector_type(4)));

// Sizes
#define HID 768
#define VOC 32000
#define TFD 1024
#define BB 4
#define TT 512
#define NROW 2048      // T*B
#define K3_NWG 96

// ---------------------------------------------------------------------------
// K0: X[r][:] = bf16(emb[tok(r)][:]), r = t*4+b ; attn=1.0f ; ctr=0
// ---------------------------------------------------------------------------
__launch_bounds__(256)
__global__ void k0_gather(const int* __restrict__ inseq, const int* __restrict__ tgt,
                          const float* __restrict__ emb, u16* __restrict__ X,
                          float* __restrict__ attn, unsigned* __restrict__ ctr) {
  int id = blockIdx.x * 256 + threadIdx.x;
  if (id == 0) *ctr = 0u;
  if (id < BB * TT) attn[id] = 1.0f;
  if (id >= NROW * 96) return;
  int r = id / 96, c = (id % 96) * 8;
  int t = r >> 2, b = r & 3;
  int tok = (t == 0) ? inseq[b * TT] : tgt[b * TT + (t - 1)];
  const float* src = emb + (size_t)tok * HID + c;
  float4 v0 = *(const float4*)(src);
  float4 v1 = *(const float4*)(src + 4);
  uint4 ov;
  ov.x = (u32)f2b(v0.x) | ((u32)f2b(v0.y) << 16);
  ov.y = (u32)f2b(v0.z) | ((u32)f2b(v0.w) << 16);
  ov.z = (u32)f2b(v1.x) | ((u32)f2b(v1.y) << 16);
  ov.w = (u32)f2b(v1.z) | ((u32)f2b(v1.w) << 16);
  *(uint4*)(X + (size_t)r * HID + c) = ov;
}

// ---------------------------------------------------------------------------
// K1: h0[b][u] = dot(tfidf[lyr[b]], lyr_W[u]) + lyr_b[u]   (all f32)
// ---------------------------------------------------------------------------
__launch_bounds__(256)
__global__ void k1_h0(const int* __restrict__ lyr, const float* __restrict__ tfidf,
                      const float* __restrict__ lyrW, const float* __restrict__ lyrb,
                      float* __restrict__ h0) {
  int id = blockIdx.x * 256 + threadIdx.x;
  if (id >= BB * HID) return;
  int b = id / HID, u = id % HID;
  const float* tr = tfidf + (size_t)lyr[b] * TFD;
  const float* wr = lyrW + (size_t)u * TFD;
  float s = 0.f;
  for (int k = 0; k < TFD; k += 4) {
    float4 t4 = *(const float4*)(tr + k);
    float4 w4 = *(const float4*)(wr + k);
    s += t4.x * w4.x + t4.y * w4.y + t4.z * w4.z + t4.w * w4.w;
  }
  h0[id] = s + lyrb[u];
}

// ---------------------------------------------------------------------------
// GEMM: C[M x N] = A[M x 768] * B^T  (A bf16 [M x 768], B f32 [N x 768] row-major)
// B converted f32->bf16 during LDS staging. 128x128 tile, 4 waves (2x2),
// 4x4 frags of v_mfma_f32_16x16x32_bf16, BK=32, LDS stride 40 (2-way = free).
// MODE 0: outp[row*N+col] = acc + bias   (GI, f32)
// MODE 1: outp[((row&3)*T + row>>2)*V + col] = acc + bias   (dec, f32)
// ---------------------------------------------------------------------------
template<int MODE>
__launch_bounds__(256)
__global__ void gemm_bt(const u16* __restrict__ A, const float* __restrict__ Bm,
                        const float* __restrict__ bias, float* __restrict__ outp,
                        int N) {
  constexpr int K = HID;
  constexpr int LD = 40;
  __shared__ u16 As[128 * LD];
  __shared__ u16 Bs[128 * LD];
  const int tid = threadIdx.x;
  const int tile_n = blockIdx.x * 128;
  const int tile_m = blockIdx.y * 128;
  const int l = tid & 63;
  const int w = tid >> 6;
  const int wm = (w >> 1) * 64, wn = (w & 1) * 64;
  const int fr = l & 15, fg = l >> 4;
  const int r0 = tid >> 2;             // staging row (0..63)
  const int kloc = (tid & 3) * 8;      // staging k offset (bf16 elems)

  f32x4 acc[4][4];
#pragma unroll
  for (int i = 0; i < 4; ++i)
#pragma unroll
    for (int j = 0; j < 4; ++j) acc[i][j] = f32x4{0.f, 0.f, 0.f, 0.f};

  for (int kk = 0; kk < K; kk += 32) {
    uint4 a0 = *(const uint4*)(A + (size_t)(tile_m + r0) * K + kk + kloc);
    uint4 a1 = *(const uint4*)(A + (size_t)(tile_m + 64 + r0) * K + kk + kloc);
    const float* bp0 = Bm + (size_t)(tile_n + r0) * K + kk + kloc;
    const float* bp1 = Bm + (size_t)(tile_n + 64 + r0) * K + kk + kloc;
    float4 b00 = *(const float4*)(bp0);
    float4 b01 = *(const float4*)(bp0 + 4);
    float4 b10 = *(const float4*)(bp1);
    float4 b11 = *(const float4*)(bp1 + 4);
    uint4 bv0, bv1;
    bv0.x = (u32)f2b(b00.x) | ((u32)f2b(b00.y) << 16);
    bv0.y = (u32)f2b(b00.z) | ((u32)f2b(b00.w) << 16);
    bv0.z = (u32)f2b(b01.x) | ((u32)f2b(b01.y) << 16);
    bv0.w = (u32)f2b(b01.z) | ((u32)f2b(b01.w) << 16);
    bv1.x = (u32)f2b(b10.x) | ((u32)f2b(b10.y) << 16);
    bv1.y = (u32)f2b(b10.z) | ((u32)f2b(b10.w) << 16);
    bv1.z = (u32)f2b(b11.x) | ((u32)f2b(b11.y) << 16);
    bv1.w = (u32)f2b(b11.z) | ((u32)f2b(b11.w) << 16);
    *(uint4*)(As + r0 * LD + kloc) = a0;
    *(uint4*)(As + (64 + r0) * LD + kloc) = a1;
    *(uint4*)(Bs + r0 * LD + kloc) = bv0;
    *(uint4*)(Bs + (64 + r0) * LD + kloc) = bv1;
    __syncthreads();
    s16x8 af[4], bf[4];
#pragma unroll
    for (int i = 0; i < 4; ++i) af[i] = *(const s16x8*)(As + (wm + i * 16 + fr) * LD + fg * 8);
#pragma unroll
    for (int j = 0; j < 4; ++j) bf[j] = *(const s16x8*)(Bs + (wn + j * 16 + fr) * LD + fg * 8);
#pragma unroll
    for (int i = 0; i < 4; ++i)
#pragma unroll
      for (int j = 0; j < 4; ++j)
        asm("v_mfma_f32_16x16x32_bf16 %0, %1, %2, %0" : "+v"(acc[i][j]) : "v"(af[i]), "v"(bf[j]));
    __syncthreads();
  }

#pragma unroll
  for (int i = 0; i < 4; ++i) {
#pragma unroll
    for (int j = 0; j < 4; ++j) {
      const int col = tile_n + wn + j * 16 + fr;
      const float bv = bias[col];
#pragma unroll
      for (int q = 0; q < 4; ++q) {
        const int row = tile_m + wm + i * 16 + fg * 4 + q;
        const float v = acc[i][j][q] + bv;
        if (MODE == 0) {
          outp[(size_t)row * N + col] = v;
        } else {
          const int b = row & 3, t = row >> 2;
          outp[((size_t)b * TT + t) * VOC + col] = v;
        }
      }
    }
  }
}

// ---------------------------------------------------------------------------
// K3: sequential GRU recurrence, all f32. 96 persistent WGs x 256 thr.
// WG owns 8 hidden units; group of 32 lanes per unit; W_hh rows in REGISTERS
// (3 gates x 6 float4 per lane). h ping-pongs in global (12KB), staged to LDS
// each step. Grid barrier per step via agent-scope atomic counter.
// ---------------------------------------------------------------------------
__launch_bounds__(256, 1)
__global__ void k3_rec(const float* __restrict__ Whh, const float* __restrict__ bhh,
                       const float* __restrict__ GI, float* hA, float* hB,
                       u16* __restrict__ Hall, float* __restrict__ hlast,
                       unsigned* ctr) {
  __shared__ float hs[BB * HID];
  const int wg = blockIdx.x, tid = threadIdx.x;
  const int grp = tid >> 5, lane32 = tid & 31;
  const int u = wg * 8 + grp;

  // weights in registers: w[g][jj] covers k = jj*128 + lane32*4 .. +3
  f32x4 wreg[3][6];
#pragma unroll
  for (int g = 0; g < 3; ++g)
#pragma unroll
    for (int jj = 0; jj < 6; ++jj)
      wreg[g][jj] = *(const f32x4*)(Whh + (size_t)(g * HID + u) * HID + jj * 128 + lane32 * 4);
  const float bs_r = bhh[u], bs_z = bhh[HID + u], bs_n = bhh[2 * HID + u];

  for (int t = 0; t < TT; ++t) {
    const float* hc = (t & 1) ? hB : hA;
    float* hnx = (t & 1) ? hA : hB;

    // stage h (3072 f32) into LDS
    {
      const float4* src = (const float4*)hc;
      float4* dst = (float4*)hs;
      for (int i = tid; i < BB * HID / 4; i += 256) dst[i] = src[i];
    }
    __syncthreads();

    float acc0[4] = {0.f, 0.f, 0.f, 0.f};
    float acc1[4] = {0.f, 0.f, 0.f, 0.f};
    float acc2[4] = {0.f, 0.f, 0.f, 0.f};
#pragma unroll
    for (int jj = 0; jj < 6; ++jj) {
      f32x4 hv[4];
#pragma unroll
      for (int b = 0; b < 4; ++b)
        hv[b] = *(const f32x4*)&hs[b * HID + jj * 128 + lane32 * 4];
#pragma unroll
      for (int b = 0; b < 4; ++b) {
        acc0[b] += wreg[0][jj].x * hv[b].x + wreg[0][jj].y * hv[b].y
                 + wreg[0][jj].z * hv[b].z + wreg[0][jj].w * hv[b].w;
        acc1[b] += wreg[1][jj].x * hv[b].x + wreg[1][jj].y * hv[b].y
                 + wreg[1][jj].z * hv[b].z + wreg[1][jj].w * hv[b].w;
        acc2[b] += wreg[2][jj].x * hv[b].x + wreg[2][jj].y * hv[b].y
                 + wreg[2][jj].z * hv[b].z + wreg[2][jj].w * hv[b].w;
      }
    }

    // reduce across the 32-lane group (masks < 32 never cross the half-wave)
#pragma unroll
    for (int off = 1; off < 32; off <<= 1) {
#pragma unroll
      for (int b = 0; b < 4; ++b) {
        acc0[b] += __shfl_xor(acc0[b], off);
        acc1[b] += __shfl_xor(acc1[b], off);
        acc2[b] += __shfl_xor(acc2[b], off);
      }
    }

    if (lane32 == 0) {
#pragma unroll
      for (int b = 0; b < 4; ++b) {
        const float* gi = GI + (size_t)(t * 4 + b) * 2304;
        float rr = 1.f / (1.f + __expf(-(gi[u] + acc0[b] + bs_r)));
        float zz = 1.f / (1.f + __expf(-(gi[HID + u] + acc1[b] + bs_z)));
        float nn = tanhf(gi[2 * HID + u] + rr * (acc2[b] + bs_n));
        float hv2 = (1.f - zz) * nn + zz * hs[b * HID + u];
        hnx[b * HID + u] = hv2;
        Hall[(size_t)(t * 4 + b) * HID + u] = f2b(hv2);
      }
    }

    // grid barrier (1/step; ping-pong h makes one barrier sufficient)
    __syncthreads();
    if (tid == 0) {
      __hip_atomic_fetch_add(ctr, 1u, __ATOMIC_RELEASE, __HIP_MEMORY_SCOPE_AGENT);
      const unsigned target = (unsigned)(t + 1) * (unsigned)K3_NWG;
      while (__hip_atomic_load(ctr, __ATOMIC_ACQUIRE, __HIP_MEMORY_SCOPE_AGENT) < target)
        __builtin_amdgcn_s_sleep(8);
    }
    __syncthreads();
  }

  // final h landed in hA (t=511 wrote hnx = hA)
  int gid = wg * 256 + tid;
  if (gid < BB * HID) hlast[gid] = hA[gid];
}

// ---------------------------------------------------------------------------
// K5: in-place log_softmax over each of 2048 rows of 32000 f32.
// Online max+sum (single read pass) + write pass.
// ---------------------------------------------------------------------------
__launch_bounds__(256)
__global__ void k5_lsm(float* __restrict__ dec) {
  float* row = dec + (size_t)blockIdx.x * VOC;
  const int tid = threadIdx.x;
  __shared__ float mred[4], sred[4];

  float m = -3.0e38f, s = 0.f;
  for (int c = tid; c < VOC / 4; c += 256) {
    float4 v = *(const float4*)(row + c * 4);
    float ml = fmaxf(fmaxf(v.x, v.y), fmaxf(v.z, v.w));
    if (ml > m) { s *= __expf(m - ml); m = ml; }
    s += __expf(v.x - m) + __expf(v.y - m) + __expf(v.z - m) + __expf(v.w - m);
  }
#pragma unroll
  for (int off = 32; off >= 1; off >>= 1) {
    float om = __shfl_xor(m, off);
    float os = __shfl_xor(s, off);
    float nm = fmaxf(m, om);
    s = s * __expf(m - nm) + os * __expf(om - nm);
    m = nm;
  }
  if ((tid & 63) == 0) { mred[tid >> 6] = m; sred[tid >> 6] = s; }
  __syncthreads();
  {
    float mm = fmaxf(fmaxf(mred[0], mred[1]), fmaxf(mred[2], mred[3]));
    float ss = sred[0] * __expf(mred[0] - mm) + sred[1] * __expf(mred[1] - mm)
             + sred[2] * __expf(mred[2] - mm) + sred[3] * __expf(mred[3] - mm);
    m = mm; s = ss;
  }
  const float lse = m + logf(s);
  __syncthreads();

  for (int c = tid; c < VOC / 4; c += 256) {
    float4 v = *(const float4*)(row + c * 4);
    v.x -= lse; v.y -= lse; v.z -= lse; v.w -= lse;
    *(float4*)(row + c * 4) = v;
  }
}

// ---------------------------------------------------------------------------
extern "C" void kernel_launch(void* const* d_in, const int* in_sizes, int n_in,
                              void* d_out, int out_size, void* d_ws, size_t ws_size,
                              hipStream_t stream) {
  const int*   lyr    = (const int*)d_in[0];
  const int*   inseq  = (const int*)d_in[1];
  const int*   tgt    = (const int*)d_in[2];
  const float* emb    = (const float*)d_in[3];
  // d_in[4..9]: Wa, ba, Ua, ub, Va, vb — dead code (softmax over 1 element => w==1, ctx==h)
  const float* tfidf  = (const float*)d_in[10];
  const float* lyrW   = (const float*)d_in[11];
  const float* lyrb   = (const float*)d_in[12];
  const float* Wih    = (const float*)d_in[13];
  const float* Whh    = (const float*)d_in[14];
  const float* bih    = (const float*)d_in[15];
  const float* bhh    = (const float*)d_in[16];
  const float* outW   = (const float*)d_in[17];
  const float* outb   = (const float*)d_in[18];

  float* out   = (float*)d_out;
  float* dec   = out;                                  // [B][T][V]
  float* hlast = out + (size_t)BB * TT * VOC;          // [1][B][H]
  float* attn  = hlast + (size_t)BB * HID;             // [B][T][1]

  char* ws = (char*)d_ws;
  u16*   X    = (u16*)(ws);                            //  3,145,728 B
  float* GI   = (float*)(ws + 3145728);                // 18,874,368 B
  u16*   Hall = (u16*)(ws + 22020096);                 //  3,145,728 B
  float* hA   = (float*)(ws + 25165824);               //     12,288 B
  float* hB   = (float*)(ws + 25178112);               //     12,288 B
  unsigned* ctr = (unsigned*)(ws + 25190400);

  k0_gather<<<768, 256, 0, stream>>>(inseq, tgt, emb, X, attn, ctr);
  k1_h0<<<12, 256, 0, stream>>>(lyr, tfidf, lyrW, lyrb, hA);
  gemm_bt<0><<<dim3(2304 / 128, NROW / 128), 256, 0, stream>>>(X, Wih, bih, GI, 2304);
  k3_rec<<<K3_NWG, 256, 0, stream>>>(Whh, bhh, GI, hA, hB, Hall, hlast, ctr);
  gemm_bt<1><<<dim3(VOC / 128, NROW / 128), 256, 0, stream>>>(Hall, outW, outb, dec, VOC);
  k5_lsm<<<NROW, 256, 0, stream>>>(dec);
}

// Round 3
// 5928.925 us; speedup vs baseline: 1.0544x; 1.0544x over previous
//
#include <hip/hip_runtime.h>

typedef unsigned short u16;
typedef unsigned int u32;

// ---------- bf16 helpers ----------
__device__ __forceinline__ u16 f2b(float f) {
  u32 u; __builtin_memcpy(&u, &f, 4);
  u32 r = (u + 0x7fffu + ((u >> 16) & 1u)) >> 16;
  return (u16)r;
}
__device__ __forceinline__ float b2f_lo(u32 v) {
  u32 u = v << 16; float f; __builtin_memcpy(&f, &u, 4); return f;
}
__device__ __forceinline__ float b2f_hi(u32 v) {
  u32 u = v & 0xffff0000u; float f; __builtin_memcpy(&f, &u, 4); return f;
}

using s16x8 = short __attribute__((ext_vector_type(8)));
using f32x4 = float __attribute__((ext_vector_type(4)));

// Sizes
#define HID 768
#define VOC 32000
#define TFD 1024
#define BB 4
#define TT 512
#define NROW 2048      // T*B
#define K3_NWG 96

// ---------------------------------------------------------------------------
// K0: X[r][:] = bf16(emb[tok(r)][:]), r = t*4+b ; attn=1.0f ; FLG zeroed
// ---------------------------------------------------------------------------
__launch_bounds__(256)
__global__ void k0_gather(const int* __restrict__ inseq, const int* __restrict__ tgt,
                          const float* __restrict__ emb, u16* __restrict__ X,
                          float* __restrict__ attn, u32* __restrict__ FLG) {
  int id = blockIdx.x * 256 + threadIdx.x;
  if (id < 128) FLG[id] = 0u;
  if (id < BB * TT) attn[id] = 1.0f;
  if (id >= NROW * 96) return;
  int r = id / 96, c = (id % 96) * 8;
  int t = r >> 2, b = r & 3;
  int tok = (t == 0) ? inseq[b * TT] : tgt[b * TT + (t - 1)];
  const float* src = emb + (size_t)tok * HID + c;
  float4 v0 = *(const float4*)(src);
  float4 v1 = *(const float4*)(src + 4);
  uint4 ov;
  ov.x = (u32)f2b(v0.x) | ((u32)f2b(v0.y) << 16);
  ov.y = (u32)f2b(v0.z) | ((u32)f2b(v0.w) << 16);
  ov.z = (u32)f2b(v1.x) | ((u32)f2b(v1.y) << 16);
  ov.w = (u32)f2b(v1.z) | ((u32)f2b(v1.w) << 16);
  *(uint4*)(X + (size_t)r * HID + c) = ov;
}

// ---------------------------------------------------------------------------
// K1: h0[b][u] = dot(tfidf[lyr[b]], lyr_W[u]) + lyr_b[u]   (all f32)
// ---------------------------------------------------------------------------
__launch_bounds__(256)
__global__ void k1_h0(const int* __restrict__ lyr, const float* __restrict__ tfidf,
                      const float* __restrict__ lyrW, const float* __restrict__ lyrb,
                      float* __restrict__ h0) {
  int id = blockIdx.x * 256 + threadIdx.x;
  if (id >= BB * HID) return;
  int b = id / HID, u = id % HID;
  const float* tr = tfidf + (size_t)lyr[b] * TFD;
  const float* wr = lyrW + (size_t)u * TFD;
  float s = 0.f;
  for (int k = 0; k < TFD; k += 4) {
    float4 t4 = *(const float4*)(tr + k);
    float4 w4 = *(const float4*)(wr + k);
    s += t4.x * w4.x + t4.y * w4.y + t4.z * w4.z + t4.w * w4.w;
  }
  h0[id] = s + lyrb[u];
}

// ---------------------------------------------------------------------------
// GEMM: C[M x N] = A[M x 768] * B^T  (A bf16 [M x 768], B f32 [N x 768] row-major)
// B converted f32->bf16 during LDS staging. 128x128 tile, 4 waves (2x2),
// 4x4 frags of v_mfma_f32_16x16x32_bf16, BK=32, LDS stride 40 (2-way = free).
// ---------------------------------------------------------------------------
template<int MODE>
__launch_bounds__(256)
__global__ void gemm_bt(const u16* __restrict__ A, const float* __restrict__ Bm,
                        const float* __restrict__ bias, float* __restrict__ outp,
                        int N) {
  constexpr int K = HID;
  constexpr int LD = 40;
  __shared__ u16 As[128 * LD];
  __shared__ u16 Bs[128 * LD];
  const int tid = threadIdx.x;
  const int tile_n = blockIdx.x * 128;
  const int tile_m = blockIdx.y * 128;
  const int l = tid & 63;
  const int w = tid >> 6;
  const int wm = (w >> 1) * 64, wn = (w & 1) * 64;
  const int fr = l & 15, fg = l >> 4;
  const int r0 = tid >> 2;             // staging row (0..63)
  const int kloc = (tid & 3) * 8;      // staging k offset (bf16 elems)

  f32x4 acc[4][4];
#pragma unroll
  for (int i = 0; i < 4; ++i)
#pragma unroll
    for (int j = 0; j < 4; ++j) acc[i][j] = f32x4{0.f, 0.f, 0.f, 0.f};

  for (int kk = 0; kk < K; kk += 32) {
    uint4 a0 = *(const uint4*)(A + (size_t)(tile_m + r0) * K + kk + kloc);
    uint4 a1 = *(const uint4*)(A + (size_t)(tile_m + 64 + r0) * K + kk + kloc);
    const float* bp0 = Bm + (size_t)(tile_n + r0) * K + kk + kloc;
    const float* bp1 = Bm + (size_t)(tile_n + 64 + r0) * K + kk + kloc;
    float4 b00 = *(const float4*)(bp0);
    float4 b01 = *(const float4*)(bp0 + 4);
    float4 b10 = *(const float4*)(bp1);
    float4 b11 = *(const float4*)(bp1 + 4);
    uint4 bv0, bv1;
    bv0.x = (u32)f2b(b00.x) | ((u32)f2b(b00.y) << 16);
    bv0.y = (u32)f2b(b00.z) | ((u32)f2b(b00.w) << 16);
    bv0.z = (u32)f2b(b01.x) | ((u32)f2b(b01.y) << 16);
    bv0.w = (u32)f2b(b01.z) | ((u32)f2b(b01.w) << 16);
    bv1.x = (u32)f2b(b10.x) | ((u32)f2b(b10.y) << 16);
    bv1.y = (u32)f2b(b10.z) | ((u32)f2b(b10.w) << 16);
    bv1.z = (u32)f2b(b11.x) | ((u32)f2b(b11.y) << 16);
    bv1.w = (u32)f2b(b11.z) | ((u32)f2b(b11.w) << 16);
    *(uint4*)(As + r0 * LD + kloc) = a0;
    *(uint4*)(As + (64 + r0) * LD + kloc) = a1;
    *(uint4*)(Bs + r0 * LD + kloc) = bv0;
    *(uint4*)(Bs + (64 + r0) * LD + kloc) = bv1;
    __syncthreads();
    s16x8 af[4], bf[4];
#pragma unroll
    for (int i = 0; i < 4; ++i) af[i] = *(const s16x8*)(As + (wm + i * 16 + fr) * LD + fg * 8);
#pragma unroll
    for (int j = 0; j < 4; ++j) bf[j] = *(const s16x8*)(Bs + (wn + j * 16 + fr) * LD + fg * 8);
#pragma unroll
    for (int i = 0; i < 4; ++i)
#pragma unroll
      for (int j = 0; j < 4; ++j)
        asm("v_mfma_f32_16x16x32_bf16 %0, %1, %2, %0" : "+v"(acc[i][j]) : "v"(af[i]), "v"(bf[j]));
    __syncthreads();
  }

#pragma unroll
  for (int i = 0; i < 4; ++i) {
#pragma unroll
    for (int j = 0; j < 4; ++j) {
      const int col = tile_n + wn + j * 16 + fr;
      const float bv = bias[col];
#pragma unroll
      for (int q = 0; q < 4; ++q) {
        const int row = tile_m + wm + i * 16 + fg * 4 + q;
        const float v = acc[i][j][q] + bv;
        if (MODE == 0) {
          outp[(size_t)row * N + col] = v;
        } else {
          const int b = row & 3, t = row >> 2;
          outp[((size_t)b * TT + t) * VOC + col] = v;
        }
      }
    }
  }
}

// ---------------------------------------------------------------------------
// K3: sequential GRU recurrence. 96 persistent WGs x 256 thr; WG owns 8 units.
// Per step: poll 96 monotonic flags (relaxed agent loads) -> acquire fence ->
// read h[t-1] (bf16, 6KB, = Hall row) -> LDS f32 -> matmul (W_hh in regs) ->
// 32-lane butterfly reduce -> gates on lanes 0..3 (1 per batch, exact f32
// h_prev carried in regs) -> store bf16 h to Hall -> release flag = t+1.
// GI loads issued at step start (latency hidden under matmul).
// ---------------------------------------------------------------------------
__launch_bounds__(256, 1)
__global__ void k3_rec(const float* __restrict__ Whh, const float* __restrict__ bhh,
                       const float* __restrict__ GI, const float* __restrict__ h0,
                       u16* __restrict__ Hall, float* __restrict__ hlast,
                       u32* __restrict__ FLG) {
  __shared__ float hs[BB * HID];
  const int wg = blockIdx.x, tid = threadIdx.x;
  const int grp = tid >> 5, lane32 = tid & 31;
  const int u = wg * 8 + grp;
  const int bb = lane32 & 3;

  // W_hh rows in registers: wreg[g][jj] covers k = jj*128 + lane32*4 .. +3
  f32x4 wreg[3][6];
#pragma unroll
  for (int g = 0; g < 3; ++g)
#pragma unroll
    for (int jj = 0; jj < 6; ++jj)
      wreg[g][jj] = *(const f32x4*)(Whh + (size_t)(g * HID + u) * HID + jj * 128 + lane32 * 4);
  const float bs_r = bhh[u], bs_z = bhh[HID + u], bs_n = bhh[2 * HID + u];

  float hown = 0.f;  // exact f32 h_prev for (u, batch=bb); valid in lanes 0..3

  for (int t = 0; t < TT; ++t) {
    // ---- wait for step t-1 broadcast
    if (t > 0) {
      if (tid < 64) {
        const u32 want = (u32)t;
        for (;;) {
          u32 a = __hip_atomic_load(FLG + tid, __ATOMIC_RELAXED, __HIP_MEMORY_SCOPE_AGENT);
          u32 b2 = (tid < 32)
                     ? __hip_atomic_load(FLG + 64 + tid, __ATOMIC_RELAXED, __HIP_MEMORY_SCOPE_AGENT)
                     : want;
          if (__all((a >= want) && (b2 >= want))) break;
          __builtin_amdgcn_s_sleep(1);
        }
      }
      __syncthreads();
      __builtin_amdgcn_fence(__ATOMIC_ACQUIRE, "agent");
    }

    // ---- stage h into LDS (f32)
    if (t == 0) {
      for (int i = tid; i < BB * HID / 4; i += 256)
        ((float4*)hs)[i] = ((const float4*)h0)[i];
    } else {
      const uint4* hr = (const uint4*)(Hall + (size_t)(t - 1) * (BB * HID));
      for (int i = tid; i < BB * HID / 8; i += 256) {
        uint4 v = hr[i];
        float4 f0, f1;
        f0.x = b2f_lo(v.x); f0.y = b2f_hi(v.x); f0.z = b2f_lo(v.y); f0.w = b2f_hi(v.y);
        f1.x = b2f_lo(v.z); f1.y = b2f_hi(v.z); f1.z = b2f_lo(v.w); f1.w = b2f_hi(v.w);
        ((float4*)hs)[i * 2] = f0;
        ((float4*)hs)[i * 2 + 1] = f1;
      }
    }

    // ---- issue this step's GI loads now; consumed after matmul (~500ns later)
    const float* gir = GI + (size_t)(t * 4 + bb) * 2304;
    const float g_r = gir[u];
    const float g_z = gir[HID + u];
    const float g_n = gir[2 * HID + u];

    __syncthreads();

    // ---- gh = W_hh[own 24 rows] . h
    float acc0[4] = {0.f, 0.f, 0.f, 0.f};
    float acc1[4] = {0.f, 0.f, 0.f, 0.f};
    float acc2[4] = {0.f, 0.f, 0.f, 0.f};
#pragma unroll
    for (int jj = 0; jj < 6; ++jj) {
      f32x4 hv[4];
#pragma unroll
      for (int b = 0; b < 4; ++b)
        hv[b] = *(const f32x4*)&hs[b * HID + jj * 128 + lane32 * 4];
#pragma unroll
      for (int b = 0; b < 4; ++b) {
        acc0[b] += wreg[0][jj].x * hv[b].x + wreg[0][jj].y * hv[b].y
                 + wreg[0][jj].z * hv[b].z + wreg[0][jj].w * hv[b].w;
        acc1[b] += wreg[1][jj].x * hv[b].x + wreg[1][jj].y * hv[b].y
                 + wreg[1][jj].z * hv[b].z + wreg[1][jj].w * hv[b].w;
        acc2[b] += wreg[2][jj].x * hv[b].x + wreg[2][jj].y * hv[b].y
                 + wreg[2][jj].z * hv[b].z + wreg[2][jj].w * hv[b].w;
      }
    }

    // ---- butterfly reduce over the 32-lane group (stays within half-wave)
#pragma unroll
    for (int off = 1; off < 32; off <<= 1) {
#pragma unroll
      for (int b = 0; b < 4; ++b) {
        acc0[b] += __shfl_xor(acc0[b], off);
        acc1[b] += __shfl_xor(acc1[b], off);
        acc2[b] += __shfl_xor(acc2[b], off);
      }
    }

    // ---- gates: lanes 0..3 of each group, one batch each (static acc select)
    if (lane32 < 4) {
      const float a0 = (bb & 2) ? ((bb & 1) ? acc0[3] : acc0[2]) : ((bb & 1) ? acc0[1] : acc0[0]);
      const float a1 = (bb & 2) ? ((bb & 1) ? acc1[3] : acc1[2]) : ((bb & 1) ? acc1[1] : acc1[0]);
      const float a2 = (bb & 2) ? ((bb & 1) ? acc2[3] : acc2[2]) : ((bb & 1) ? acc2[1] : acc2[0]);
      if (t == 0) hown = hs[bb * HID + u];
      const float rr = 1.f / (1.f + __expf(-(g_r + a0 + bs_r)));
      const float zz = 1.f / (1.f + __expf(-(g_z + a1 + bs_z)));
      const float nn = tanhf(g_n + rr * (a2 + bs_n));
      const float hv = (1.f - zz) * nn + zz * hown;
      hown = hv;
      Hall[(size_t)(t * 4 + bb) * HID + u] = f2b(hv);
    }

    __syncthreads();  // drain all waves' Hall stores (vmcnt(0) per wave) before release
    if (tid == 0)
      __hip_atomic_store(FLG + wg, (u32)(t + 1), __ATOMIC_RELEASE, __HIP_MEMORY_SCOPE_AGENT);
  }

  // exact f32 h_last: each WG writes its own 32 values from registers
  if (lane32 < 4) hlast[bb * HID + u] = hown;
}

// ---------------------------------------------------------------------------
// K5: in-place log_softmax over each of 2048 rows of 32000 f32.
// ---------------------------------------------------------------------------
__launch_bounds__(256)
__global__ void k5_lsm(float* __restrict__ dec) {
  float* row = dec + (size_t)blockIdx.x * VOC;
  const int tid = threadIdx.x;
  __shared__ float mred[4], sred[4];

  float m = -3.0e38f, s = 0.f;
  for (int c = tid; c < VOC / 4; c += 256) {
    float4 v = *(const float4*)(row + c * 4);
    float ml = fmaxf(fmaxf(v.x, v.y), fmaxf(v.z, v.w));
    if (ml > m) { s *= __expf(m - ml); m = ml; }
    s += __expf(v.x - m) + __expf(v.y - m) + __expf(v.z - m) + __expf(v.w - m);
  }
#pragma unroll
  for (int off = 32; off >= 1; off >>= 1) {
    float om = __shfl_xor(m, off);
    float os = __shfl_xor(s, off);
    float nm = fmaxf(m, om);
    s = s * __expf(m - nm) + os * __expf(om - nm);
    m = nm;
  }
  if ((tid & 63) == 0) { mred[tid >> 6] = m; sred[tid >> 6] = s; }
  __syncthreads();
  {
    float mm = fmaxf(fmaxf(mred[0], mred[1]), fmaxf(mred[2], mred[3]));
    float ss = sred[0] * __expf(mred[0] - mm) + sred[1] * __expf(mred[1] - mm)
             + sred[2] * __expf(mred[2] - mm) + sred[3] * __expf(mred[3] - mm);
    m = mm; s = ss;
  }
  const float lse = m + logf(s);
  __syncthreads();

  for (int c = tid; c < VOC / 4; c += 256) {
    float4 v = *(const float4*)(row + c * 4);
    v.x -= lse; v.y -= lse; v.z -= lse; v.w -= lse;
    *(float4*)(row + c * 4) = v;
  }
}

// ---------------------------------------------------------------------------
extern "C" void kernel_launch(void* const* d_in, const int* in_sizes, int n_in,
                              void* d_out, int out_size, void* d_ws, size_t ws_size,
                              hipStream_t stream) {
  const int*   lyr    = (const int*)d_in[0];
  const int*   inseq  = (const int*)d_in[1];
  const int*   tgt    = (const int*)d_in[2];
  const float* emb    = (const float*)d_in[3];
  // d_in[4..9]: Wa, ba, Ua, ub, Va, vb — dead code (softmax over 1 element => w==1, ctx==h)
  const float* tfidf  = (const float*)d_in[10];
  const float* lyrW   = (const float*)d_in[11];
  const float* lyrb   = (const float*)d_in[12];
  const float* Wih    = (const float*)d_in[13];
  const float* Whh    = (const float*)d_in[14];
  const float* bih    = (const float*)d_in[15];
  const float* bhh    = (const float*)d_in[16];
  const float* outW   = (const float*)d_in[17];
  const float* outb   = (const float*)d_in[18];

  float* out   = (float*)d_out;
  float* dec   = out;                                  // [B][T][V]
  float* hlast = out + (size_t)BB * TT * VOC;          // [1][B][H]
  float* attn  = hlast + (size_t)BB * HID;             // [B][T][1]

  char* ws = (char*)d_ws;
  u16*   X    = (u16*)(ws);                            //  3,145,728 B
  float* GI   = (float*)(ws + 3145728);                // 18,874,368 B
  u16*   Hall = (u16*)(ws + 22020096);                 //  3,145,728 B  (= h broadcast, [t*4+b][u])
  float* hA   = (float*)(ws + 25165824);               //     12,288 B
  u32*   FLG  = (u32*)(ws + 25178112);                 //        512 B

  k0_gather<<<768, 256, 0, stream>>>(inseq, tgt, emb, X, attn, FLG);
  k1_h0<<<12, 256, 0, stream>>>(lyr, tfidf, lyrW, lyrb, hA);
  gemm_bt<0><<<dim3(2304 / 128, NROW / 128), 256, 0, stream>>>(X, Wih, bih, GI, 2304);
  k3_rec<<<K3_NWG, 256, 0, stream>>>(Whh, bhh, GI, hA, Hall, hlast, FLG);
  gemm_bt<1><<<dim3(VOC / 128, NROW / 128), 256, 0, stream>>>(Hall, outW, outb, dec, VOC);
  k5_lsm<<<NROW, 256, 0, stream>>>(dec);
}